// Round 1
// baseline (133.408 us; speedup 1.0000x reference)
//
#include <hip/hip_runtime.h>

// Problem constants (fixed by reference)
#define BATCH   16384
#define NFEAT   512
#define NTREE   64
#define NDEPTH  6
#define NLEAF   64
#define NDOUT   64
#define NLOGIT  384   // NDEPTH * NTREE

typedef float  f32x4  __attribute__((ext_vector_type(4)));
typedef short  short8 __attribute__((ext_vector_type(8)));

union U8 { unsigned short u[8]; short8 v; };

// round-to-nearest-even fp32 -> bf16 (bit trick; inputs are normal finite values)
__device__ __forceinline__ unsigned short f2bf(float f) {
    union { float f; unsigned int u; } c; c.f = f;
    unsigned int r = c.u + 0x7FFFu + ((c.u >> 16) & 1u);
    return (unsigned short)(r >> 16);
}

// ---------------------------------------------------------------------------
// Kernel 0: V2[t][d][l] = bf16( leaf_values[t][l][d] / 64 )
// One block per tree; LDS transpose; coalesced in and out.
// ---------------------------------------------------------------------------
__global__ __launch_bounds__(256) void prep_v(const float* __restrict__ V,
                                              unsigned short* __restrict__ V2) {
    __shared__ float Vt[64 * 65];
    const int t = blockIdx.x, tid = threadIdx.x;
    const float* src = V + (size_t)t * 4096;
    for (int j = 0; j < 4; ++j) {
        int idx = tid + 256 * j;            // 0..1023
        int l = idx >> 4, d4 = idx & 15;
        float4 v = *(const float4*)(src + l * 64 + d4 * 4);
        Vt[l * 65 + d4 * 4 + 0] = v.x;
        Vt[l * 65 + d4 * 4 + 1] = v.y;
        Vt[l * 65 + d4 * 4 + 2] = v.z;
        Vt[l * 65 + d4 * 4 + 3] = v.w;
    }
    __syncthreads();
    unsigned short* dst = V2 + (size_t)t * 4096;
    for (int j = 0; j < 4; ++j) {
        int idx = tid + 256 * j;
        int d = idx >> 4, l4 = idx & 15;
        ushort4 u;
        u.x = f2bf(Vt[(l4 * 4 + 0) * 65 + d] * 0.015625f);
        u.y = f2bf(Vt[(l4 * 4 + 1) * 65 + d] * 0.015625f);
        u.z = f2bf(Vt[(l4 * 4 + 2) * 65 + d] * 0.015625f);
        u.w = f2bf(Vt[(l4 * 4 + 3) * 65 + d] * 0.015625f);
        *(ushort4*)(dst + d * 64 + l4 * 4) = u;
    }
}

// ---------------------------------------------------------------------------
// Kernel 1: SPT[n][b] = sigmoid( sum_f x[b][f]*Wflat[f][n] + bias[n] )
//   n = d*64 + t  (d=level, t=tree), stored TRANSPOSED (n-major) in fp32.
// 128x128 tile, BK=32, bf16 MFMA 16x16x32, 4 waves each own a 64x64 quadrant.
// LDS row stride 40 bf16 (80B): 16B-aligned b128 reads, 2-way conflicts (free).
// W tile stored transposed [n][k] with k XOR-swizzled by (n>>2)&3.
// ---------------------------------------------------------------------------
__global__ __launch_bounds__(256) void gemm1(const float* __restrict__ x,
                                             const float* __restrict__ W,
                                             const float* __restrict__ bias,
                                             float* __restrict__ SPT) {
    __shared__ unsigned short As[128 * 40];
    __shared__ unsigned short Ws[128 * 40];
    const int tid  = threadIdx.x;
    const int wave = tid >> 6, lane = tid & 63;
    const int quad = lane >> 4, l15 = lane & 15;
    const int wm = wave & 1, wn = wave >> 1;   // wave quadrant within 128x128
    const int bm = blockIdx.x, bn = blockIdx.y;

    f32x4 acc[4][4];
    for (int mt = 0; mt < 4; ++mt)
        for (int nt = 0; nt < 4; ++nt)
            acc[mt][nt] = (f32x4){0.f, 0.f, 0.f, 0.f};

    for (int k0 = 0; k0 < NFEAT; k0 += 32) {
        // ---- stage A (x tile: 128 rows x 32 k), fp32 -> bf16
        for (int j = 0; j < 4; ++j) {
            int idx = tid + 256 * j;         // 0..1023 float4s
            int row = idx >> 3, c4 = idx & 7;
            float4 v = *(const float4*)(x + (size_t)(bm * 128 + row) * NFEAT + k0 + c4 * 4);
            ushort4 u;
            u.x = f2bf(v.x); u.y = f2bf(v.y); u.z = f2bf(v.z); u.w = f2bf(v.w);
            *(ushort4*)(As + row * 40 + c4 * 4) = u;
        }
        // ---- stage W transposed: Ws[n][k ^ swz], n local col, k local f
        for (int j = 0; j < 4; ++j) {
            int idx = tid + 256 * j;         // 0..1023 float4s
            int h = idx >> 9, rem = idx & 511;
            int f = rem >> 4, c4 = rem & 15;
            int d = bn * 2 + h;
            float4 v = *(const float4*)(W + ((size_t)(d * 512 + k0 + f)) * 64 + c4 * 4);
            int kk = f ^ ((c4 & 3) << 3);    // (n>>2)&3 == c4&3 for these 4 n's
            int nb = h * 64 + c4 * 4;
            Ws[(nb + 0) * 40 + kk] = f2bf(v.x);
            Ws[(nb + 1) * 40 + kk] = f2bf(v.y);
            Ws[(nb + 2) * 40 + kk] = f2bf(v.z);
            Ws[(nb + 3) * 40 + kk] = f2bf(v.w);
        }
        __syncthreads();

        short8 aF[4], bF[4];
        for (int mt = 0; mt < 4; ++mt)
            aF[mt] = *(const short8*)(As + (wm * 64 + mt * 16 + l15) * 40 + quad * 8);
        for (int nt = 0; nt < 4; ++nt) {
            int n_loc = wn * 64 + nt * 16 + l15;
            int kk = (quad * 8) ^ (((n_loc >> 2) & 3) << 3);
            bF[nt] = *(const short8*)(Ws + n_loc * 40 + kk);
        }
        for (int mt = 0; mt < 4; ++mt)
            for (int nt = 0; nt < 4; ++nt)
                acc[mt][nt] = __builtin_amdgcn_mfma_f32_16x16x32_bf16(
                    aF[mt], bF[nt], acc[mt][nt], 0, 0, 0);
        __syncthreads();
    }

    // ---- epilogue: bias + sigmoid, store transposed SPT[n][b]
    // D layout: col = lane&15, row = quad*4 + reg  -> 4 consecutive b per lane.
    for (int nt = 0; nt < 4; ++nt) {
        int n = bn * 128 + wn * 64 + nt * 16 + l15;
        float bv = bias[n];
        for (int mt = 0; mt < 4; ++mt) {
            int row = bm * 128 + wm * 64 + mt * 16 + quad * 4;
            float4 o;
            float z0 = acc[mt][nt][0] + bv;
            float z1 = acc[mt][nt][1] + bv;
            float z2 = acc[mt][nt][2] + bv;
            float z3 = acc[mt][nt][3] + bv;
            o.x = 1.0f / (1.0f + __expf(-z0));
            o.y = 1.0f / (1.0f + __expf(-z1));
            o.z = 1.0f / (1.0f + __expf(-z2));
            o.w = 1.0f / (1.0f + __expf(-z3));
            *(float4*)(SPT + (size_t)n * BATCH + row) = o;
        }
    }
}

// ---------------------------------------------------------------------------
// Kernel 2: out[b][d] += sum_{t in chunk} sum_l P[b,t,l] * V2[t][d][l]
// Grid (BATCH/128, 4): 128-row tile x 16-tree chunk. 4 waves x 32 rows each.
// P computed in-register (factored: ~33 mults per 16 leaf-probs per lane),
// rounded once to bf16 as MFMA A-fragments. K per tree = 64 leaves = 2 ksteps.
// ---------------------------------------------------------------------------
__global__ __launch_bounds__(256) void tree_gemm(const float* __restrict__ SPT,
                                                 const unsigned short* __restrict__ V2,
                                                 float* __restrict__ out) {
    __shared__ float sp[96 * 128];          // [d*16+tt][row]  48 KB
    __shared__ unsigned short Vs[64 * 72];  // [dout][leaf] pad 72, 9 KB
    const int tid  = threadIdx.x;
    const int wave = tid >> 6, lane = tid & 63;
    const int quad = lane >> 4, l15 = lane & 15;
    const int bm = blockIdx.x;
    const int t0 = blockIdx.y * 16;

    // stage split-prob block: rows n = d*64 + (t0..t0+15), cols = 128 batch
    for (int j = 0; j < 12; ++j) {
        int idx = tid + 256 * j;            // 0..3071 float4s
        int row = idx >> 5, c4 = idx & 31;
        int d = row >> 4, tt = row & 15;
        int n = d * 64 + t0 + tt;
        *(float4*)(sp + row * 128 + c4 * 4) =
            *(const float4*)(SPT + (size_t)n * BATCH + bm * 128 + c4 * 4);
    }

    f32x4 acc[2][4];
    for (int mt = 0; mt < 2; ++mt)
        for (int nt = 0; nt < 4; ++nt)
            acc[mt][nt] = (f32x4){0.f, 0.f, 0.f, 0.f};

    for (int tl = 0; tl < 16; ++tl) {
        __syncthreads();                    // sp ready (iter 0) / Vs readers done
        // stage V2[t] -> Vs (already bf16, pre-transposed, pre-scaled)
        for (int j = 0; j < 2; ++j) {
            int idx = tid + 256 * j;        // 0..511 16B-chunks
            int row = idx >> 3, c8 = idx & 7;
            *(uint4*)(Vs + row * 72 + c8 * 8) =
                *(const uint4*)(V2 + ((size_t)(t0 + tl) * 4096 + row * 64 + c8 * 8));
        }
        __syncthreads();

        // B fragments: B[k=leaf][n=dout], lane: n=l15, k=quad*8+j (+32*ks)
        short8 bF[4][2];
        for (int nt = 0; nt < 4; ++nt)
            for (int ks = 0; ks < 2; ++ks)
                bF[nt][ks] = *(const short8*)(Vs + (nt * 16 + l15) * 72 + ks * 32 + quad * 8);

        // A fragments: P values. leaf l = ks*32 + quad*8 + j
        // level0<->bit5=ks, level1<->bit4=quad>>1, level2<->bit3=quad&1,
        // levels3/4/5 <-> bits2/1/0 = j
        short8 aF[2][2];
        for (int mt = 0; mt < 2; ++mt) {
            int rloc = wave * 32 + mt * 16 + l15;
            float p0 = sp[(0 * 16 + tl) * 128 + rloc];
            float p1 = sp[(1 * 16 + tl) * 128 + rloc];
            float p2 = sp[(2 * 16 + tl) * 128 + rloc];
            float p3 = sp[(3 * 16 + tl) * 128 + rloc];
            float p4 = sp[(4 * 16 + tl) * 128 + rloc];
            float p5 = sp[(5 * 16 + tl) * 128 + rloc];
            float q1 = (quad & 2) ? (1.0f - p1) : p1;
            float q2 = (quad & 1) ? (1.0f - p2) : p2;
            float pre  = q1 * q2;
            float pre0 = p0 * pre;
            float pre1 = (1.0f - p0) * pre;
            float t3a = p3, t3b = 1.0f - p3;
            float t4a = p4, t4b = 1.0f - p4;
            float t5a = p5, t5b = 1.0f - p5;
            float t34[4] = { t3a * t4a, t3a * t4b, t3b * t4a, t3b * t4b };
            U8 a0, a1;
            #pragma unroll
            for (int j = 0; j < 8; ++j) {
                float wj = t34[j >> 1] * ((j & 1) ? t5b : t5a);
                a0.u[j] = f2bf(pre0 * wj);
                a1.u[j] = f2bf(pre1 * wj);
            }
            aF[mt][0] = a0.v;
            aF[mt][1] = a1.v;
        }

        for (int mt = 0; mt < 2; ++mt)
            for (int nt = 0; nt < 4; ++nt)
                for (int ks = 0; ks < 2; ++ks)
                    acc[mt][nt] = __builtin_amdgcn_mfma_f32_16x16x32_bf16(
                        aF[mt][ks], bF[nt][ks], acc[mt][nt], 0, 0, 0);
    }

    // epilogue: 4 tree-chunk partials per output element
    for (int mt = 0; mt < 2; ++mt)
        for (int nt = 0; nt < 4; ++nt)
            for (int r = 0; r < 4; ++r) {
                int b = bm * 128 + wave * 32 + mt * 16 + quad * 4 + r;
                int d = nt * 16 + l15;
                atomicAdd(out + (size_t)b * NDOUT + d, acc[mt][nt][r]);
            }
}

// ---------------------------------------------------------------------------
extern "C" void kernel_launch(void* const* d_in, const int* in_sizes, int n_in,
                              void* d_out, int out_size, void* d_ws, size_t ws_size,
                              hipStream_t stream) {
    const float* x    = (const float*)d_in[0];  // (16384, 512)
    const float* W    = (const float*)d_in[1];  // (6, 512, 64)
    const float* bias = (const float*)d_in[2];  // (6, 64) flat = 384
    const float* leaf = (const float*)d_in[3];  // (64, 64, 64)
    float* out = (float*)d_out;                 // (16384, 64)

    // ws layout: SPT fp32 [384][16384] (25.17 MB) | V2 bf16 [64][64][64] (0.5 MB)
    float* SPT = (float*)d_ws;
    unsigned short* V2 = (unsigned short*)((char*)d_ws + (size_t)NLOGIT * BATCH * 4);

    prep_v<<<64, 256, 0, stream>>>(leaf, V2);
    gemm1<<<dim3(BATCH / 128, NLOGIT / 128), 256, 0, stream>>>(x, W, bias, SPT);
    hipMemsetAsync(d_out, 0, (size_t)out_size * sizeof(float), stream);
    tree_gemm<<<dim3(BATCH / 128, 4), 256, 0, stream>>>(SPT, V2, out);
}